// Round 7
// baseline (331.851 us; speedup 1.0000x reference)
//
#include <hip/hip_runtime.h>
#include <math.h>

#define N_   8
#define C_   64
#define H_   128
#define W_   128
#define HW_  (H_ * W_)
#define CHW_ (C_ * HW_)
#define K_   3
#define CI_TILE 8
#define CO_BLK  16
#define N_CG    (C_ / CO_BLK)   // 4 co-groups
#define TILE 16
#define HALO (TILE + 2)          // 18
// Row stride 24 floats: rows' bank windows rotate by 24 (mod 32) -> the wave's
// rows x 16 cols land exactly 2 lanes/bank (free on CDNA4, m136).
#define XSTRIDE 24
#define CISZ (HALO * XSTRIDE)    // floats per ci plane (432)
#define WROW 12                  // padded weight row (9 used) -> 16B-aligned rows
#define WCI  (CO_BLK * WROW)     // 192 floats per ci
#define WSTRIDE (C_ * K_ * K_)   // 576 floats between consecutive co's
#define BN_EPS 1e-5
#define POW_EPS 1e-12f

// One |x-w| accumulate in EXACTLY 2 VALU instructions; both operands VGPR now
// (weights come from LDS broadcast reads, not SGPRs -> no SMEM in the loop,
// so lgkmcnt stays DS-only and the compiler uses precise counted waits
// instead of full drains).
#define MAC_TERM(accv, wv, xvk) do { float t_;                         \
    asm("v_sub_f32 %1, %2, %3\n\t"                                     \
        "v_add_f32 %0, %0, |%1|"                                       \
        : "+v"(accv), "=&v"(t_)                                        \
        : "v"(wv), "v"(xvk));                                          \
  } while (0)

__global__ __launch_bounds__(256, 8) void adder_kernel(
    const float* __restrict__ x, const float* __restrict__ weight,
    float* __restrict__ y, double* __restrict__ sums)
{
    __shared__ __align__(16) float sx[CI_TILE * CISZ];   // 13824 B
    __shared__ __align__(16) float wl[CI_TILE * WCI];    //  6144 B
    __shared__ float red[CO_BLK][2][4];                  // stat partials

    const int tx = threadIdx.x & 15;
    const int ty = threadIdx.x >> 4;
    const int tile_h = blockIdx.x >> 3;   // H_/TILE = 8 tiles
    const int tile_w = blockIdx.x & 7;    // W_/TILE = 8 tiles
    const int n   = blockIdx.y;
    const int co0 = blockIdx.z * CO_BLK;
    const int h0 = tile_h * TILE;
    const int w0 = tile_w * TILE;

    float acc[CO_BLK];
#pragma unroll
    for (int j = 0; j < CO_BLK; ++j) acc[j] = 0.f;

    const float* xn = x + n * CHW_;

    // ---- One-time affine staging offsets (ci-affine inside chunks) ----
    // x halo plane = 18*18 = 324 elems: thread t covers idx=t, and t<68 also
    // covers idx=256+t. Per-thread: 2 LDS offsets + 2 global offsets (-1 = pad).
    int lx1, gx1, lx2 = -1, gx2 = -1;
    {
        int idx = threadIdx.x;
        int r = idx / HALO, c = idx - r * HALO;
        int gh = h0 + r - 1, gw = w0 + c - 1;
        lx1 = r * XSTRIDE + c;
        gx1 = ((unsigned)gh < (unsigned)H_ && (unsigned)gw < (unsigned)W_)
              ? (gh * W_ + gw) : -1;
        if (threadIdx.x < HALO * HALO - 256) {   // 68 threads
            idx = 256 + threadIdx.x;
            r = idx / HALO; c = idx - r * HALO;
            gh = h0 + r - 1; gw = w0 + c - 1;
            lx2 = r * XSTRIDE + c;
            gx2 = ((unsigned)gh < (unsigned)H_ && (unsigned)gw < (unsigned)W_)
                  ? (gh * W_ + gw) : -1;
        }
    }
    // weight slice: threads 0..143 each own one (co,k); loop ci is affine.
    int wlo = -1, wgo = 0;
    if (threadIdx.x < CO_BLK * 9) {
        int co = threadIdx.x / 9, k = threadIdx.x - co * 9;
        wlo = co * WROW + k;
        wgo = (co0 + co) * WSTRIDE + k;
    }

    for (int cb = 0; cb < C_; cb += CI_TILE) {
        const float* xncb = xn + cb * HW_;
        __syncthreads();  // previous chunk fully read before overwrite
#pragma unroll
        for (int ci = 0; ci < CI_TILE; ++ci) {
            float v = (gx1 >= 0) ? xncb[ci * HW_ + gx1] : 0.f;
            sx[ci * CISZ + lx1] = v;
        }
        if (lx2 >= 0) {
#pragma unroll
            for (int ci = 0; ci < CI_TILE; ++ci) {
                float v = (gx2 >= 0) ? xncb[ci * HW_ + gx2] : 0.f;
                sx[ci * CISZ + lx2] = v;
            }
        }
        if (wlo >= 0) {
            const float* wgp = weight + wgo + cb * 9;
#pragma unroll
            for (int ci = 0; ci < CI_TILE; ++ci)
                wl[ci * WCI + wlo] = wgp[ci * 9];
        }
        __syncthreads();

#pragma unroll 1
        for (int ci = 0; ci < CI_TILE; ++ci) {
            const float* sxc = &sx[ci * CISZ];
            float xv[9];
#pragma unroll
            for (int kh = 0; kh < 3; ++kh)
#pragma unroll
                for (int kw = 0; kw < 3; ++kw)
                    xv[kh * 3 + kw] = sxc[(ty + kh) * XSTRIDE + tx + kw];

            const float* wrow = &wl[ci * WCI];
#pragma unroll
            for (int j = 0; j < CO_BLK; ++j) {
                // 9 weights via 2x ds_read_b128 + 1x ds_read_b32, uniform
                // address (broadcast, conflict-free), row 16B-aligned.
                float4 wa = *reinterpret_cast<const float4*>(wrow + j * WROW);
                float4 wb = *reinterpret_cast<const float4*>(wrow + j * WROW + 4);
                float  w8 = wrow[j * WROW + 8];
                MAC_TERM(acc[j], wa.x, xv[0]);
                MAC_TERM(acc[j], wa.y, xv[1]);
                MAC_TERM(acc[j], wa.z, xv[2]);
                MAC_TERM(acc[j], wa.w, xv[3]);
                MAC_TERM(acc[j], wb.x, xv[4]);
                MAC_TERM(acc[j], wb.y, xv[5]);
                MAC_TERM(acc[j], wb.z, xv[6]);
                MAC_TERM(acc[j], wb.w, xv[7]);
                MAC_TERM(acc[j], w8,   xv[8]);
            }
        }
    }

    // Epilogue: y = -acc + residual x; fused per-channel sum/sumsq for BN.
    const int pix = (h0 + ty) * W_ + (w0 + tx);
    float* yo = y + n * CHW_ + co0 * HW_ + pix;
    const float* xr = xn + co0 * HW_ + pix;
    const int lane = threadIdx.x & 63;
    const int wid  = threadIdx.x >> 6;

#pragma unroll
    for (int j = 0; j < CO_BLK; ++j) {
        float v = -acc[j] + xr[j * HW_];
        yo[j * HW_] = v;
        float s = v, ss = v * v;
#pragma unroll
        for (int off = 32; off > 0; off >>= 1) {
            s  += __shfl_down(s, off);
            ss += __shfl_down(ss, off);
        }
        if (lane == 0) { red[j][0][wid] = s; red[j][1][wid] = ss; }
    }
    __syncthreads();
    if (threadIdx.x < CO_BLK) {
        int j = threadIdx.x;
        float S  = red[j][0][0] + red[j][0][1] + red[j][0][2] + red[j][0][3];
        float SS = red[j][1][0] + red[j][1][1] + red[j][1][2] + red[j][1][3];
        atomicAdd(&sums[co0 + j], (double)S);
        atomicAdd(&sums[C_ + co0 + j], (double)SS);
    }
}

// Per-channel scale/shift from batch stats.
__global__ void finalize_kernel(const double* __restrict__ sums,
                                const float* __restrict__ gamma,
                                const float* __restrict__ beta,
                                float* __restrict__ sc)
{
    const int c = threadIdx.x;  // 64 threads
    const double cnt = (double)(N_ * HW_);
    double mean = sums[c] / cnt;
    double var  = sums[C_ + c] / cnt - mean * mean;
    float inv   = (float)(1.0 / sqrt(var + (double)BN_EPS));
    float scale = gamma[c] * inv;
    float shift = beta[c] - (float)mean * scale;
    sc[c]      = scale;
    sc[C_ + c] = shift;
}

// In-place BN affine + power activation, float4 vectorized.
// alpha==1 fast path: sign(t)*(|t|+1e-12)^1 = t +- 1e-12 (below tolerance).
__global__ __launch_bounds__(256) void apply_kernel(
    float* __restrict__ y, const float* __restrict__ sc,
    const float* __restrict__ alpha_p)
{
    const int idx = blockIdx.x * 256 + threadIdx.x;   // float4 index
    const float alpha = alpha_p[0];
    const int e0 = idx * 4;
    const int c = (e0 / HW_) & (C_ - 1);   // HW_ divisible by 4: all 4 in same channel
    const float scale = sc[c];
    const float shift = sc[C_ + c];

    float4 v = reinterpret_cast<float4*>(y)[idx];
    float* pv = reinterpret_cast<float*>(&v);
    if (alpha == 1.0f) {
#pragma unroll
        for (int i = 0; i < 4; ++i)
            pv[i] = pv[i] * scale + shift;
    } else {
#pragma unroll
        for (int i = 0; i < 4; ++i) {
            float t = pv[i] * scale + shift;
            float sgn = (t > 0.f) ? 1.f : ((t < 0.f) ? -1.f : 0.f);
            pv[i] = sgn * powf(fabsf(t) + POW_EPS, alpha);
        }
    }
    reinterpret_cast<float4*>(y)[idx] = v;
}

extern "C" void kernel_launch(void* const* d_in, const int* in_sizes, int n_in,
                              void* d_out, int out_size, void* d_ws, size_t ws_size,
                              hipStream_t stream)
{
    const float* x      = (const float*)d_in[0];
    const float* weight = (const float*)d_in[1];
    const float* gamma  = (const float*)d_in[2];
    const float* beta   = (const float*)d_in[3];
    const float* alpha  = (const float*)d_in[4];
    float* out = (float*)d_out;

    double* sums = (double*)d_ws;                                // 128 doubles
    float*  sc   = (float*)((char*)d_ws + 128 * sizeof(double)); // 128 floats

    hipMemsetAsync(d_ws, 0, 128 * sizeof(double), stream);

    adder_kernel<<<dim3(64, N_, N_CG), 256, 0, stream>>>(x, weight, out, sums);
    finalize_kernel<<<1, C_, 0, stream>>>(sums, gamma, beta, sc);

    const int n4 = (N_ * CHW_) / 4;           // 2,097,152 float4s
    apply_kernel<<<n4 / 256, 256, 0, stream>>>(out, sc, alpha);
}

// Round 8
// 313.640 us; speedup vs baseline: 1.0581x; 1.0581x over previous
//
#include <hip/hip_runtime.h>
#include <math.h>

#define N_   8
#define C_   64
#define H_   128
#define W_   128
#define HW_  (H_ * W_)
#define CHW_ (C_ * HW_)
#define K_   3
#define CI_TILE 8
#define CO_BLK  16
#define N_CG    (C_ / CO_BLK)   // 4 co-groups
#define TILE_H 16
#define TILE_W 32               // 2 horizontal pixels per thread
#define HALO_H (TILE_H + 2)      // 18
#define HALO_W (TILE_W + 2)      // 34
#define XSTR   36                // padded row stride (b64-aligned, uniform banks)
#define CISZ   (HALO_H * XSTR)   // 648 floats per ci plane
#define PLANE  (HALO_H * HALO_W) // 612 staged elems per ci plane
#define WROW 12                  // padded weight row (9 used) -> 16B-aligned
#define WCI  (CO_BLK * WROW)     // 192 floats per ci
#define WSTRIDE (C_ * K_ * K_)   // 576 floats between consecutive co's
#define BN_EPS 1e-5
#define POW_EPS 1e-12f

// One |x-w| accumulate in EXACTLY 2 VALU instructions (VGPR operands).
#define MAC_TERM(accv, wv, xvk) do { float t_;                         \
    asm("v_sub_f32 %1, %2, %3\n\t"                                     \
        "v_add_f32 %0, %0, |%1|"                                       \
        : "+v"(accv), "=&v"(t_)                                        \
        : "v"(wv), "v"(xvk));                                          \
  } while (0)

// R5/R6/R7 all pinned at ~277us with three different weight paths (SGPR
// chunked / SGPR pipelined / LDS broadcast): the invariant is shared-pipe
// fetch ops per MAC (~1:5). This version register-tiles 2 horizontal pixels
// per thread so every weight/x fetch feeds 2x the MACs (1:10.7), and halves
// staging + epilogue + barrier cost per output.
__global__ __launch_bounds__(256, 4) void adder_kernel(
    const float* __restrict__ x, const float* __restrict__ weight,
    float* __restrict__ y, double* __restrict__ sums)
{
    __shared__ __align__(16) float sx[CI_TILE * CISZ];   // 20736 B
    __shared__ __align__(16) float wl[CI_TILE * WCI];    //  6144 B
    __shared__ float red[CO_BLK][2][4];                  // stat partials

    const int tx2 = threadIdx.x & 15;       // pixel-pair column index
    const int ty  = threadIdx.x >> 4;       // row 0..15
    const int tile_h = blockIdx.x >> 2;     // 8 tiles of 16 rows
    const int tile_w = blockIdx.x & 3;      // 4 tiles of 32 cols
    const int n   = blockIdx.y;
    const int co0 = blockIdx.z * CO_BLK;
    const int h0 = tile_h * TILE_H;
    const int w0 = tile_w * TILE_W;

    float acc0[CO_BLK], acc1[CO_BLK];
#pragma unroll
    for (int j = 0; j < CO_BLK; ++j) { acc0[j] = 0.f; acc1[j] = 0.f; }

    const float* xn = x + n * CHW_;

    // ---- One-time affine staging offsets (3 slots cover the 612-elem plane;
    // ci loop adds HW_ / CISZ). gx<0 encodes zero-fill padding. ----
    int lx[3], gx[3];
#pragma unroll
    for (int s = 0; s < 3; ++s) {
        int idx = threadIdx.x + s * 256;
        if (idx < PLANE) {
            int r = idx / HALO_W, c = idx - r * HALO_W;
            int gh = h0 + r - 1, gw = w0 + c - 1;
            lx[s] = r * XSTR + c;
            gx[s] = ((unsigned)gh < (unsigned)H_ && (unsigned)gw < (unsigned)W_)
                    ? (gh * W_ + gw) : -1;
        } else { lx[s] = -1; gx[s] = -1; }
    }
    // weight slice: threads 0..143 each own one (co,k); ci loop affine.
    int wlo = -1, wgo = 0;
    if (threadIdx.x < CO_BLK * 9) {
        int co = threadIdx.x / 9, k = threadIdx.x - co * 9;
        wlo = co * WROW + k;
        wgo = (co0 + co) * WSTRIDE + k;
    }

    for (int cb = 0; cb < C_; cb += CI_TILE) {
        const float* xncb = xn + cb * HW_;
        __syncthreads();  // previous chunk fully read before overwrite
#pragma unroll
        for (int ci = 0; ci < CI_TILE; ++ci) {
            float v0 = (gx[0] >= 0) ? xncb[ci * HW_ + gx[0]] : 0.f;
            sx[ci * CISZ + lx[0]] = v0;
            float v1 = (gx[1] >= 0) ? xncb[ci * HW_ + gx[1]] : 0.f;
            sx[ci * CISZ + lx[1]] = v1;
        }
        if (lx[2] >= 0) {
#pragma unroll
            for (int ci = 0; ci < CI_TILE; ++ci) {
                float v = (gx[2] >= 0) ? xncb[ci * HW_ + gx[2]] : 0.f;
                sx[ci * CISZ + lx[2]] = v;
            }
        }
        if (wlo >= 0) {
            const float* wgp = weight + wgo + cb * 9;
#pragma unroll
            for (int ci = 0; ci < CI_TILE; ++ci)
                wl[ci * WCI + wlo] = wgp[ci * 9];
        }
        __syncthreads();

#pragma unroll 1
        for (int ci = 0; ci < CI_TILE; ++ci) {
            const float* sxc = &sx[ci * CISZ];
            const int cbase = 2 * tx2;
            // 3 rows x 4 cols window serves both pixels: 6x ds_read_b64,
            // banks uniform (16 lanes x 2 dwords = all 32 banks per row).
            float xr0[4], xr1[4], xr2[4];
            {
                float2 a = *(const float2*)(sxc + (ty + 0) * XSTR + cbase);
                float2 b = *(const float2*)(sxc + (ty + 0) * XSTR + cbase + 2);
                xr0[0] = a.x; xr0[1] = a.y; xr0[2] = b.x; xr0[3] = b.y;
            }
            {
                float2 a = *(const float2*)(sxc + (ty + 1) * XSTR + cbase);
                float2 b = *(const float2*)(sxc + (ty + 1) * XSTR + cbase + 2);
                xr1[0] = a.x; xr1[1] = a.y; xr1[2] = b.x; xr1[3] = b.y;
            }
            {
                float2 a = *(const float2*)(sxc + (ty + 2) * XSTR + cbase);
                float2 b = *(const float2*)(sxc + (ty + 2) * XSTR + cbase + 2);
                xr2[0] = a.x; xr2[1] = a.y; xr2[2] = b.x; xr2[3] = b.y;
            }

            const float* wrow = &wl[ci * WCI];
#pragma unroll
            for (int j = 0; j < CO_BLK; ++j) {
                float4 wa = *(const float4*)(wrow + j * WROW);
                float4 wb = *(const float4*)(wrow + j * WROW + 4);
                float  w8 = wrow[j * WROW + 8];
                // two independent accumulate chains (px0 / px1) per j
                MAC_TERM(acc0[j], wa.x, xr0[0]); MAC_TERM(acc1[j], wa.x, xr0[1]);
                MAC_TERM(acc0[j], wa.y, xr0[1]); MAC_TERM(acc1[j], wa.y, xr0[2]);
                MAC_TERM(acc0[j], wa.z, xr0[2]); MAC_TERM(acc1[j], wa.z, xr0[3]);
                MAC_TERM(acc0[j], wa.w, xr1[0]); MAC_TERM(acc1[j], wa.w, xr1[1]);
                MAC_TERM(acc0[j], wb.x, xr1[1]); MAC_TERM(acc1[j], wb.x, xr1[2]);
                MAC_TERM(acc0[j], wb.y, xr1[2]); MAC_TERM(acc1[j], wb.y, xr1[3]);
                MAC_TERM(acc0[j], wb.z, xr2[0]); MAC_TERM(acc1[j], wb.z, xr2[1]);
                MAC_TERM(acc0[j], wb.w, xr2[1]); MAC_TERM(acc1[j], wb.w, xr2[2]);
                MAC_TERM(acc0[j], w8,   xr2[2]); MAC_TERM(acc1[j], w8,   xr2[3]);
            }
        }
    }

    // Epilogue: y = -acc + residual (float2); fused per-channel sum/sumsq.
    const int pix = (h0 + ty) * W_ + (w0 + 2 * tx2);
    float* yo = y + n * CHW_ + co0 * HW_ + pix;
    const float* xrp = xn + co0 * HW_ + pix;
    const int lane = threadIdx.x & 63;
    const int wid  = threadIdx.x >> 6;

#pragma unroll
    for (int j = 0; j < CO_BLK; ++j) {
        float2 rv = *(const float2*)(xrp + j * HW_);
        float v0 = -acc0[j] + rv.x;
        float v1 = -acc1[j] + rv.y;
        float2 ov; ov.x = v0; ov.y = v1;
        *(float2*)(yo + j * HW_) = ov;
        float s = v0 + v1, ss = v0 * v0 + v1 * v1;
#pragma unroll
        for (int off = 32; off > 0; off >>= 1) {
            s  += __shfl_down(s, off);
            ss += __shfl_down(ss, off);
        }
        if (lane == 0) { red[j][0][wid] = s; red[j][1][wid] = ss; }
    }
    __syncthreads();
    if (threadIdx.x < CO_BLK) {
        int j = threadIdx.x;
        float S  = red[j][0][0] + red[j][0][1] + red[j][0][2] + red[j][0][3];
        float SS = red[j][1][0] + red[j][1][1] + red[j][1][2] + red[j][1][3];
        atomicAdd(&sums[co0 + j], (double)S);
        atomicAdd(&sums[C_ + co0 + j], (double)SS);
    }
}

// Per-channel scale/shift from batch stats.
__global__ void finalize_kernel(const double* __restrict__ sums,
                                const float* __restrict__ gamma,
                                const float* __restrict__ beta,
                                float* __restrict__ sc)
{
    const int c = threadIdx.x;  // 64 threads
    const double cnt = (double)(N_ * HW_);
    double mean = sums[c] / cnt;
    double var  = sums[C_ + c] / cnt - mean * mean;
    float inv   = (float)(1.0 / sqrt(var + (double)BN_EPS));
    float scale = gamma[c] * inv;
    float shift = beta[c] - (float)mean * scale;
    sc[c]      = scale;
    sc[C_ + c] = shift;
}

// In-place BN affine + power activation, float4 vectorized.
// alpha==1 fast path: sign(t)*(|t|+1e-12)^1 = t +- 1e-12 (below tolerance).
__global__ __launch_bounds__(256) void apply_kernel(
    float* __restrict__ y, const float* __restrict__ sc,
    const float* __restrict__ alpha_p)
{
    const int idx = blockIdx.x * 256 + threadIdx.x;   // float4 index
    const float alpha = alpha_p[0];
    const int e0 = idx * 4;
    const int c = (e0 / HW_) & (C_ - 1);   // HW_ divisible by 4: all 4 in same channel
    const float scale = sc[c];
    const float shift = sc[C_ + c];

    float4 v = reinterpret_cast<float4*>(y)[idx];
    float* pv = reinterpret_cast<float*>(&v);
    if (alpha == 1.0f) {
#pragma unroll
        for (int i = 0; i < 4; ++i)
            pv[i] = pv[i] * scale + shift;
    } else {
#pragma unroll
        for (int i = 0; i < 4; ++i) {
            float t = pv[i] * scale + shift;
            float sgn = (t > 0.f) ? 1.f : ((t < 0.f) ? -1.f : 0.f);
            pv[i] = sgn * powf(fabsf(t) + POW_EPS, alpha);
        }
    }
    reinterpret_cast<float4*>(y)[idx] = v;
}

extern "C" void kernel_launch(void* const* d_in, const int* in_sizes, int n_in,
                              void* d_out, int out_size, void* d_ws, size_t ws_size,
                              hipStream_t stream)
{
    const float* x      = (const float*)d_in[0];
    const float* weight = (const float*)d_in[1];
    const float* gamma  = (const float*)d_in[2];
    const float* beta   = (const float*)d_in[3];
    const float* alpha  = (const float*)d_in[4];
    float* out = (float*)d_out;

    double* sums = (double*)d_ws;                                // 128 doubles
    float*  sc   = (float*)((char*)d_ws + 128 * sizeof(double)); // 128 floats

    hipMemsetAsync(d_ws, 0, 128 * sizeof(double), stream);

    adder_kernel<<<dim3(32, N_, N_CG), 256, 0, stream>>>(x, weight, out, sums);
    finalize_kernel<<<1, C_, 0, stream>>>(sums, gamma, beta, sc);

    const int n4 = (N_ * CHW_) / 4;           // 2,097,152 float4s
    apply_kernel<<<n4 / 256, 256, 0, stream>>>(out, sc, alpha);
}